// Round 1
// 2903.957 us; speedup vs baseline: 1.1982x; 1.1982x over previous
//
#include <hip/hip_runtime.h>
#include <stdint.h>

// RWKV forward, MI355X. Round 3: depth-2 pipelined GEMM (4 LDS buffers,
// counted vmcnt(8), raw s_barrier — T3+T4 minimal form) replacing the serial
// 2-barrier K-loop (was latency-bound at 2 blocks/CU, MfmaUtil 21%).
// Also fused ln+mix into one kernel (saves x round-trip + 12 launches).

#define LNUM 6
#define HD   1024
#define AD   1024
#define TT   2048
#define NTOK 8192
#define EPSF 1e-5f
#define NEGF (-1e38f)

#define WKV_C  32            // chunk length
#define WKV_NC 64            // chunks per channel (WKV_C * WKV_NC == TT)
#define NCH    4096          // B * A channels

typedef __attribute__((ext_vector_type(8))) short bf16x8;
typedef __attribute__((ext_vector_type(4))) float f32x4;

__device__ __forceinline__ unsigned short f2bf(float f) {
  union { float f; uint32_t u; } c; c.f = f;
  uint32_t r = c.u + 0x7fffu + ((c.u >> 16) & 1u);
  return (unsigned short)(r >> 16);
}

// async global->LDS, 16B per lane; lds dest must be wave-uniform base (+lane*16 implicit)
__device__ __forceinline__ void gld_lds16(const void* g, const void* l) {
  __builtin_amdgcn_global_load_lds(
      (const __attribute__((address_space(1))) void*)(uintptr_t)g,
      (__attribute__((address_space(3))) void*)(uint32_t)(uintptr_t)l,
      16, 0, 0);
}

enum { EP_NONE = 0, EP_SIG = 1, EP_RELUSQ = 2, EP_ADD = 3, EP_MULADD = 4 };

// C[n,m] = sum_k A[n,k]*B[m,k]; A:[NTOK,K] bf16 row-major, B:[M,K] bf16 row-major.
// Depth-2 pipeline: 4 LDS buffers; STAGE(t+2) issued at iter top; counted
// vmcnt(8) keeps 2 tiles in flight across the (single, raw) barrier per iter.
template <int EPI>
__global__ __launch_bounds__(256) void gemm_nt(
    const unsigned short* __restrict__ Aact,
    const unsigned short* __restrict__ Bw,
    float* __restrict__ Co,
    unsigned short* __restrict__ Cb,
    const float* __restrict__ aux,
    int K, int M)
{
  __shared__ unsigned short sA[4][128 * 32];
  __shared__ unsigned short sB[4][128 * 32];
  const int tid  = threadIdx.x;
  const int lane = tid & 63;
  const int wave = tid >> 6;
  const int quad = lane >> 4;
  const int r16  = lane & 15;
  const int wm = wave >> 1, wn = wave & 1;
  const int m0 = blockIdx.x * 128;   // activation rows
  const int n0 = blockIdx.y * 128;   // weight rows (output cols)

  f32x4 acc[4][4];
#pragma unroll
  for (int i = 0; i < 4; ++i)
#pragma unroll
    for (int j = 0; j < 4; ++j) acc[i][j] = (f32x4){0.f, 0.f, 0.f, 0.f};

  const int wbase = wave * 64;
  const int nk = K >> 5;

  // staging geometry: 512 x 16B chunks per tile-pair; this thread owns chunk
  // tid (it=0) and 256+tid (it=1); lds linear dest chunk == source chunk.
  const int row0 = tid >> 2,          kc0 = tid & 3;
  const int row1 = (256 + tid) >> 2,  kc1 = (256 + tid) & 3;

  auto STAGE = [&](int buf, int kt) {
    const int k0 = kt << 5;
    gld_lds16(Aact + (size_t)(m0 + row0) * K + k0 + kc0 * 8,
              (const char*)sA[buf] + wbase * 16);
    gld_lds16(Bw   + (size_t)(n0 + row0) * K + k0 + kc0 * 8,
              (const char*)sB[buf] + wbase * 16);
    gld_lds16(Aact + (size_t)(m0 + row1) * K + k0 + kc1 * 8,
              (const char*)sA[buf] + (256 + wbase) * 16);
    gld_lds16(Bw   + (size_t)(n0 + row1) * K + k0 + kc1 * 8,
              (const char*)sB[buf] + (256 + wbase) * 16);
  };

  STAGE(0, 0);
  if (nk > 1) STAGE(1, 1);

  for (int kt = 0; kt < nk; ++kt) {
    if (kt + 2 < nk) {
      STAGE((kt + 2) & 3, kt + 2);
      // 12 outstanding; wait until <=8 -> the 4 oldest (tile kt) have landed
      asm volatile("s_waitcnt vmcnt(8)" ::: "memory");
    } else if (kt + 1 < nk) {
      asm volatile("s_waitcnt vmcnt(4)" ::: "memory");
    } else {
      asm volatile("s_waitcnt vmcnt(0)" ::: "memory");
    }
    __builtin_amdgcn_s_barrier();       // all waves' tile-kt stages complete
    asm volatile("" ::: "memory");      // no LDS reads hoisted above barrier

    const unsigned short* a_s = sA[kt & 3];
    const unsigned short* b_s = sB[kt & 3];
    bf16x8 af[4], bfr[4];
#pragma unroll
    for (int i = 0; i < 4; ++i) {
      af[i]  = *(const bf16x8*)(a_s + (wm * 64 + i * 16 + r16) * 32 + quad * 8);
      bfr[i] = *(const bf16x8*)(b_s + (wn * 64 + i * 16 + r16) * 32 + quad * 8);
    }
#pragma unroll
    for (int i = 0; i < 4; ++i)
#pragma unroll
      for (int j = 0; j < 4; ++j)
        acc[i][j] = __builtin_amdgcn_mfma_f32_16x16x32_bf16(af[i], bfr[j], acc[i][j], 0, 0, 0);
    // no trailing barrier: next write of buf[kt&3] is STAGE(kt+4), two
    // barriers away; wave skew is bounded to one barrier interval.
  }

#pragma unroll
  for (int i = 0; i < 4; ++i) {
    const int ar = m0 + wm * 64 + i * 16 + quad * 4;
#pragma unroll
    for (int j = 0; j < 4; ++j) {
      const int cc = n0 + wn * 64 + j * 16 + r16;
#pragma unroll
      for (int r = 0; r < 4; ++r) {
        const size_t idx = (size_t)(ar + r) * M + cc;
        const float v = acc[i][j][r];
        if constexpr (EPI == EP_NONE)   Co[idx] = v;
        if constexpr (EPI == EP_SIG)    Co[idx] = 1.f / (1.f + __expf(-v));
        if constexpr (EPI == EP_RELUSQ) { const float t = fmaxf(v, 0.f); Cb[idx] = f2bf(t * t); }
        if constexpr (EPI == EP_ADD)    Co[idx] += v;
        if constexpr (EPI == EP_MULADD) Co[idx] += aux[idx] * v;
      }
    }
  }
}

// LayerNorm over H=1024; optional embedding gather when ids != nullptr.
__global__ __launch_bounds__(256) void ln_kernel(
    const float* __restrict__ in, const int* __restrict__ ids,
    const float* __restrict__ emb,
    const float* __restrict__ gw, const float* __restrict__ gb,
    float* __restrict__ out)
{
  const int n = blockIdx.x, tid = threadIdx.x;
  const float* src = ids ? (emb + (size_t)ids[n] * HD) : (in + (size_t)n * HD);
  const float4 v = ((const float4*)src)[tid];
  float s  = v.x + v.y + v.z + v.w;
  float s2 = v.x * v.x + v.y * v.y + v.z * v.z + v.w * v.w;
#pragma unroll
  for (int off = 32; off > 0; off >>= 1) {
    s  += __shfl_down(s, off);
    s2 += __shfl_down(s2, off);
  }
  __shared__ float red[8];
  const int wv = tid >> 6, ln = tid & 63;
  if (ln == 0) { red[wv] = s; red[4 + wv] = s2; }
  __syncthreads();
  if (tid == 0) {
    const float S  = red[0] + red[1] + red[2] + red[3];
    const float S2 = red[4] + red[5] + red[6] + red[7];
    const float mu = S * (1.f / HD);
    const float var = S2 * (1.f / HD) - mu * mu;
    red[0] = mu; red[1] = rsqrtf(var + EPSF);
  }
  __syncthreads();
  const float mu = red[0], rs = red[1];
  const float4 w4 = ((const float4*)gw)[tid];
  const float4 b4 = ((const float4*)gb)[tid];
  float4 o;
  o.x = (v.x - mu) * rs * w4.x + b4.x;
  o.y = (v.y - mu) * rs * w4.y + b4.y;
  o.z = (v.z - mu) * rs * w4.z + b4.z;
  o.w = (v.w - mu) * rs * w4.w + b4.w;
  ((float4*)(out + (size_t)n * HD))[tid] = o;
}

// Fused LayerNorm + token-shift mix: per token n, LN(h[n]) and LN(h[n-1])
// computed in-register (prev is zero at t==0), then m*x + (1-m)*prev -> bf16.
__global__ __launch_bounds__(256) void lnmix_kernel(
    const float* __restrict__ h,
    const float* __restrict__ gw, const float* __restrict__ gb,
    const float* __restrict__ m0p, const float* __restrict__ m1p, const float* __restrict__ m2p,
    ushort4* __restrict__ o0, ushort4* __restrict__ o1, ushort4* __restrict__ o2)
{
  const int n = blockIdx.x, tid = threadIdx.x;
  const int t = n & (TT - 1);
  const float4 vc = ((const float4*)(h + (size_t)n * HD))[tid];
  float4 vp = make_float4(0.f, 0.f, 0.f, 0.f);
  if (t != 0) vp = ((const float4*)(h + (size_t)(n - 1) * HD))[tid];

  float sc  = vc.x + vc.y + vc.z + vc.w;
  float sc2 = vc.x * vc.x + vc.y * vc.y + vc.z * vc.z + vc.w * vc.w;
  float sp  = vp.x + vp.y + vp.z + vp.w;
  float sp2 = vp.x * vp.x + vp.y * vp.y + vp.z * vp.z + vp.w * vp.w;
#pragma unroll
  for (int off = 32; off > 0; off >>= 1) {
    sc  += __shfl_down(sc, off);
    sc2 += __shfl_down(sc2, off);
    sp  += __shfl_down(sp, off);
    sp2 += __shfl_down(sp2, off);
  }
  __shared__ float red[16];
  const int wv = tid >> 6, ln = tid & 63;
  if (ln == 0) { red[wv] = sc; red[4 + wv] = sc2; red[8 + wv] = sp; red[12 + wv] = sp2; }
  __syncthreads();
  if (tid == 0) {
    float S  = red[0] + red[1] + red[2] + red[3];
    float S2 = red[4] + red[5] + red[6] + red[7];
    float mu = S * (1.f / HD);
    float var = S2 * (1.f / HD) - mu * mu;
    red[0] = mu; red[1] = rsqrtf(var + EPSF);
    S  = red[8] + red[9] + red[10] + red[11];
    S2 = red[12] + red[13] + red[14] + red[15];
    mu = S * (1.f / HD);
    var = S2 * (1.f / HD) - mu * mu;
    red[2] = mu; red[3] = rsqrtf(var + EPSF);
  }
  __syncthreads();
  const float muc = red[0], rsc = red[1];
  const float mup = red[2], rsp = red[3];
  const float4 w4 = ((const float4*)gw)[tid];
  const float4 b4 = ((const float4*)gb)[tid];
  float4 xc, xp;
  xc.x = (vc.x - muc) * rsc * w4.x + b4.x;
  xc.y = (vc.y - muc) * rsc * w4.y + b4.y;
  xc.z = (vc.z - muc) * rsc * w4.z + b4.z;
  xc.w = (vc.w - muc) * rsc * w4.w + b4.w;
  if (t != 0) {
    xp.x = (vp.x - mup) * rsp * w4.x + b4.x;
    xp.y = (vp.y - mup) * rsp * w4.y + b4.y;
    xp.z = (vp.z - mup) * rsp * w4.z + b4.z;
    xp.w = (vp.w - mup) * rsp * w4.w + b4.w;
  } else {
    xp = make_float4(0.f, 0.f, 0.f, 0.f);
  }

  const size_t o = (size_t)n * 256 + tid;
  float4 m = ((const float4*)m0p)[tid];
  ushort4 r;
  r.x = f2bf(m.x * xc.x + (1.f - m.x) * xp.x);
  r.y = f2bf(m.y * xc.y + (1.f - m.y) * xp.y);
  r.z = f2bf(m.z * xc.z + (1.f - m.z) * xp.z);
  r.w = f2bf(m.w * xc.w + (1.f - m.w) * xp.w);
  o0[o] = r;
  m = ((const float4*)m1p)[tid];
  r.x = f2bf(m.x * xc.x + (1.f - m.x) * xp.x);
  r.y = f2bf(m.y * xc.y + (1.f - m.y) * xp.y);
  r.z = f2bf(m.z * xc.z + (1.f - m.z) * xp.z);
  r.w = f2bf(m.w * xc.w + (1.f - m.w) * xp.w);
  o1[o] = r;
  if (o2) {
    m = ((const float4*)m2p)[tid];
    r.x = f2bf(m.x * xc.x + (1.f - m.x) * xp.x);
    r.y = f2bf(m.y * xc.y + (1.f - m.y) * xp.y);
    r.z = f2bf(m.z * xc.z + (1.f - m.z) * xp.z);
    r.w = f2bf(m.w * xc.w + (1.f - m.w) * xp.w);
    o2[o] = r;
  }
}

// ---- blocked WKV ----
// channel c = b*AD + a.  k/v/r layout: [(b*TT + t) * AD + a].
// Phase 1: per (channel, chunk) local transform (la, lb, lp) from zero init.
__global__ __launch_bounds__(256) void wkv_p1(
    const float* __restrict__ kx, const float* __restrict__ vx,
    const float* __restrict__ tdecay,
    float* __restrict__ la, float* __restrict__ lb, float* __restrict__ lp)
{
  const int c = blockIdx.x * 256 + threadIdx.x;
  const int a = c & (AD - 1);
  const int b = c >> 10;
  const int j = blockIdx.y;
  const float w = -__expf(tdecay[a]);
  const size_t base = ((size_t)b * TT + (size_t)j * WKV_C) * AD + a;
  float A = 0.f, Bb = 0.f, p = NEGF;
#pragma unroll 4
  for (int t = 0; t < WKV_C; ++t) {
    const float kt = kx[base + (size_t)t * AD];
    const float vt = vx[base + (size_t)t * AD];
    const float pn = fmaxf(p + w, kt);
    const float s1 = __expf(p + w - pn);
    const float s2 = __expf(kt - pn);
    A = s1 * A + s2 * vt;
    Bb = s1 * Bb + s2;
    p = pn;
  }
  const int o = j * NCH + c;
  la[o] = A; lb[o] = Bb; lp[o] = p;
}

// Phase 2: per channel, exclusive prefix combine over chunks.
__global__ __launch_bounds__(256) void wkv_p2(
    const float* __restrict__ la, const float* __restrict__ lb,
    const float* __restrict__ lp, const float* __restrict__ tdecay,
    float* __restrict__ sa, float* __restrict__ sb, float* __restrict__ sp)
{
  const int c = blockIdx.x * 256 + threadIdx.x;
  const int a = c & (AD - 1);
  const float wC = -__expf(tdecay[a]) * (float)WKV_C;
  float A = 0.f, Bb = 0.f, p = NEGF;
  for (int j = 0; j < WKV_NC; ++j) {
    const int o = j * NCH + c;
    sa[o] = A; sb[o] = Bb; sp[o] = p;
    const float A2 = la[o], B2 = lb[o], p2 = lp[o];
    const float pn = fmaxf(p + wC, p2);
    const float e1 = __expf(p + wC - pn);
    const float e2 = __expf(p2 - pn);
    A = e1 * A + e2 * A2;
    Bb = e1 * Bb + e2 * B2;
    p = pn;
  }
}

// Phase 3: re-run reference step per chunk from incoming state; fused r*y -> bf16.
__global__ __launch_bounds__(256) void wkv_p3(
    const float* __restrict__ kx, const float* __restrict__ vx,
    const float* __restrict__ rx,
    const float* __restrict__ tfirst, const float* __restrict__ tdecay,
    const float* __restrict__ sa, const float* __restrict__ sb,
    const float* __restrict__ sp,
    unsigned short* __restrict__ ry)
{
  const int c = blockIdx.x * 256 + threadIdx.x;
  const int a = c & (AD - 1);
  const int b = c >> 10;
  const int j = blockIdx.y;
  const float u = tfirst[a];
  const float w = -__expf(tdecay[a]);
  const size_t base = ((size_t)b * TT + (size_t)j * WKV_C) * AD + a;
  const int o = j * NCH + c;
  float A = sa[o], Bb = sb[o], p = sp[o];
#pragma unroll 2
  for (int t = 0; t < WKV_C; ++t) {
    const size_t off = base + (size_t)t * AD;
    const float kt = kx[off], vt = vx[off];
    const float q  = fmaxf(p, u + kt);
    const float wt = __expf(u + kt - q);
    const float sc = __expf(p - q);
    const float y  = (A * sc + wt * vt) / (Bb * sc + wt);
    ry[off] = f2bf(y * rx[off]);
    const float pn = fmaxf(p + w, kt);
    const float s1 = __expf(p + w - pn);
    const float s2 = __expf(kt - pn);
    A = s1 * A + s2 * vt;
    Bb = s1 * Bb + s2;
    p = pn;
  }
}

__global__ __launch_bounds__(256) void f2b_kernel(const float* __restrict__ in,
                                                  unsigned short* __restrict__ out, int n4)
{
  const int i = blockIdx.x * 256 + threadIdx.x;
  if (i >= n4) return;
  const float4 v = ((const float4*)in)[i];
  ushort4 r;
  r.x = f2bf(v.x); r.y = f2bf(v.y); r.z = f2bf(v.z); r.w = f2bf(v.w);
  ((ushort4*)out)[i] = r;
}

extern "C" void kernel_launch(void* const* d_in, const int* in_sizes, int n_in,
                              void* d_out, int out_size, void* d_ws, size_t ws_size,
                              hipStream_t stream)
{
  (void)in_sizes; (void)n_in; (void)out_size; (void)ws_size;
  const int*   ids   = (const int*)d_in[0];
  const float* emb   = (const float*)d_in[1];
  const float* prew  = (const float*)d_in[2];
  const float* preb  = (const float*)d_in[3];
  const float* postw = (const float*)d_in[4];
  const float* postb = (const float*)d_in[5];
  const float* ln1w  = (const float*)d_in[6];
  const float* ln1b  = (const float*)d_in[7];
  const float* ln2w  = (const float*)d_in[8];
  const float* ln2b  = (const float*)d_in[9];
  const float* amk   = (const float*)d_in[10];
  const float* amv   = (const float*)d_in[11];
  const float* amr   = (const float*)d_in[12];
  const float* awk   = (const float*)d_in[13];
  const float* awv   = (const float*)d_in[14];
  const float* awr   = (const float*)d_in[15];
  const float* awo   = (const float*)d_in[16];
  const float* td    = (const float*)d_in[17];
  const float* tf    = (const float*)d_in[18];
  const float* fmk   = (const float*)d_in[19];
  const float* fmr   = (const float*)d_in[20];
  const float* fwk   = (const float*)d_in[21];
  const float* fwr   = (const float*)d_in[22];
  const float* fwv   = (const float*)d_in[23];

  char* ws = (char*)d_ws;
  float* h  = (float*)(ws + 0);                         // 32MB fp32 [8192,1024]
  float* x  = (float*)(ws + 33554432);                  // 32MB fp32 (WKV scratch)
  float* kb = (float*)(ws + 67108864);                  // 32MB fp32
  float* vb = (float*)(ws + 100663296);                 // 32MB fp32
  float* rb = (float*)(ws + 134217728);                 // 32MB fp32
  unsigned short* ab = (unsigned short*)(ws + 167772160); // 64MB bf16 [8192,4096]
  unsigned short* wb = (unsigned short*)(ws + 234881024); // 27MB bf16 per-layer weights

  unsigned short* xk = ab;
  unsigned short* xv = ab + 8388608;
  unsigned short* xr = ab + 16777216;
  unsigned short* ry = ab + 25165824;

  // WKV scratch lives in x (free during attention's WKV): 6 x NC*NCH floats = 6MB
  float* wla = x;
  float* wlb = x + WKV_NC * NCH;
  float* wlp = x + 2 * WKV_NC * NCH;
  float* wsa = x + 3 * WKV_NC * NCH;
  float* wsb = x + 4 * WKV_NC * NCH;
  float* wsp = x + 5 * WKV_NC * NCH;

  const dim3 blk(256);
  const dim3 g1(NTOK / 128, 1024 / 128);
  const dim3 g2(NTOK / 128, 4096 / 128);
  const dim3 gw(NCH / 256, WKV_NC);

  ln_kernel<<<NTOK, blk, 0, stream>>>(nullptr, ids, emb, prew, preb, h);

  for (int i = 0; i < LNUM; ++i) {
    // per-layer weights -> bf16
    f2b_kernel<<<1024, blk, 0, stream>>>(awk + (size_t)i * 1048576, wb + 0,       262144);
    f2b_kernel<<<1024, blk, 0, stream>>>(awv + (size_t)i * 1048576, wb + 1048576, 262144);
    f2b_kernel<<<1024, blk, 0, stream>>>(awr + (size_t)i * 1048576, wb + 2097152, 262144);
    f2b_kernel<<<1024, blk, 0, stream>>>(awo + (size_t)i * 1048576, wb + 3145728, 262144);
    f2b_kernel<<<4096, blk, 0, stream>>>(fwk + (size_t)i * 4194304, wb + 4194304, 1048576);
    f2b_kernel<<<1024, blk, 0, stream>>>(fwr + (size_t)i * 1048576, wb + 8388608, 262144);
    f2b_kernel<<<4096, blk, 0, stream>>>(fwv + (size_t)i * 4194304, wb + 9437184, 1048576);

    // attention
    lnmix_kernel<<<NTOK, blk, 0, stream>>>(h, ln1w + i * HD, ln1b + i * HD,
                                           amk + i * HD, amv + i * HD, amr + i * HD,
                                           (ushort4*)xk, (ushort4*)xv, (ushort4*)xr);
    gemm_nt<EP_NONE><<<g1, blk, 0, stream>>>(xk, wb + 0,       kb, nullptr, nullptr, 1024, 1024);
    gemm_nt<EP_NONE><<<g1, blk, 0, stream>>>(xv, wb + 1048576, vb, nullptr, nullptr, 1024, 1024);
    gemm_nt<EP_SIG ><<<g1, blk, 0, stream>>>(xr, wb + 2097152, rb, nullptr, nullptr, 1024, 1024);
    wkv_p1<<<gw, blk, 0, stream>>>(kb, vb, td + i * AD, wla, wlb, wlp);
    wkv_p2<<<NCH / 256, blk, 0, stream>>>(wla, wlb, wlp, td + i * AD, wsa, wsb, wsp);
    wkv_p3<<<gw, blk, 0, stream>>>(kb, vb, rb, tf + i * AD, td + i * AD, wsa, wsb, wsp, ry);
    gemm_nt<EP_ADD ><<<g1, blk, 0, stream>>>(ry, wb + 3145728, h, nullptr, nullptr, 1024, 1024);

    // ffn
    lnmix_kernel<<<NTOK, blk, 0, stream>>>(h, ln2w + i * HD, ln2b + i * HD,
                                           fmk + i * HD, fmr + i * HD, nullptr,
                                           (ushort4*)kb, (ushort4*)vb, nullptr);
    gemm_nt<EP_RELUSQ><<<g2, blk, 0, stream>>>((unsigned short*)kb, wb + 4194304, nullptr, ab, nullptr, 1024, 4096);
    gemm_nt<EP_SIG   ><<<g1, blk, 0, stream>>>((unsigned short*)vb, wb + 8388608, rb, nullptr, nullptr, 1024, 1024);
    gemm_nt<EP_MULADD><<<g1, blk, 0, stream>>>(ab, wb + 9437184, h, nullptr, rb, 4096, 1024);
  }

  ln_kernel<<<NTOK, blk, 0, stream>>>(h, nullptr, nullptr, postw, postb, (float*)d_out);
}

// Round 2
// 2750.248 us; speedup vs baseline: 1.2652x; 1.0559x over previous
//
#include <hip/hip_runtime.h>
#include <stdint.h>

// RWKV forward, MI355X. Round 4: T2 LDS XOR-swizzle on the GEMM (kills the
// 8-way bank conflict on ds_read_b128 that the R3 pipeline exposed), fused
// K/V/R GEMMs into one z=3 launch, fused the 7 weight-cast launches into one.

#define LNUM 6
#define HD   1024
#define AD   1024
#define TT   2048
#define NTOK 8192
#define EPSF 1e-5f
#define NEGF (-1e38f)

#define WKV_C  32            // chunk length
#define WKV_NC 64            // chunks per channel (WKV_C * WKV_NC == TT)
#define NCH    4096          // B * A channels

typedef __attribute__((ext_vector_type(8))) short bf16x8;
typedef __attribute__((ext_vector_type(4))) float f32x4;

__device__ __forceinline__ unsigned short f2bf(float f) {
  union { float f; uint32_t u; } c; c.f = f;
  uint32_t r = c.u + 0x7fffu + ((c.u >> 16) & 1u);
  return (unsigned short)(r >> 16);
}

// async global->LDS, 16B per lane; lds dest must be wave-uniform base (+lane*16 implicit)
__device__ __forceinline__ void gld_lds16(const void* g, const void* l) {
  __builtin_amdgcn_global_load_lds(
      (const __attribute__((address_space(1))) void*)(uintptr_t)g,
      (__attribute__((address_space(3))) void*)(uint32_t)(uintptr_t)l,
      16, 0, 0);
}

enum { EP_NONE = 0, EP_SIG = 1, EP_RELUSQ = 2, EP_ADD = 3, EP_MULADD = 4, EP_KVR = 5 };

// C[n,m] = sum_k A[n,k]*B[m,k]; A:[NTOK,K] bf16 row-major, B:[M,K] bf16 row-major.
// Depth-2 pipeline: 4 LDS buffers; STAGE(t+2) at iter top; counted vmcnt(8)
// keeps 2 tiles in flight across the single raw barrier per iter.
// LDS swizzle (T2, both-sides): row's four 16B chunks are permuted by
// kc' = kc ^ ((row>>1)&3), applied to the GLOBAL source address (LDS dest is
// linear, required by global_load_lds) and to the ds_read offset. This spreads
// each quarter-wave's b128 reads uniformly over all 8 bank-quads (2 lanes
// each = free) instead of 8-way on 2 bank-quads.
// EP_KVR: blockIdx.z in {0,1,2} selects A/B/C by fixed strides; z==2 applies
// sigmoid (the r path), else plain store.
template <int EPI>
__global__ __launch_bounds__(256) void gemm_nt(
    const unsigned short* __restrict__ Aact,
    const unsigned short* __restrict__ Bw,
    float* __restrict__ Co,
    unsigned short* __restrict__ Cb,
    const float* __restrict__ aux,
    int K, int M)
{
  __shared__ unsigned short sA[4][128 * 32];
  __shared__ unsigned short sB[4][128 * 32];
  const int tid  = threadIdx.x;
  const int lane = tid & 63;
  const int wave = tid >> 6;
  const int quad = lane >> 4;
  const int r16  = lane & 15;
  const int wm = wave >> 1, wn = wave & 1;
  const int m0 = blockIdx.x * 128;   // activation rows
  const int n0 = blockIdx.y * 128;   // weight rows (output cols)

  if constexpr (EPI == EP_KVR) {
    const int z = blockIdx.z;
    Aact += (size_t)z * 8388608;     // xk/xv/xr, each [8192,1024] bf16
    Bw   += (size_t)z * 1048576;     // wk/wv/wr, each [1024,1024] bf16
    Co   += (size_t)z * 8388608;     // kb/vb/rb, each [8192,1024] f32
  }

  f32x4 acc[4][4];
#pragma unroll
  for (int i = 0; i < 4; ++i)
#pragma unroll
    for (int j = 0; j < 4; ++j) acc[i][j] = (f32x4){0.f, 0.f, 0.f, 0.f};

  const int wbase = wave * 64;
  const int nk = K >> 5;

  // staging geometry: 512 x 16B chunks per tile; thread owns lds slot tid and
  // 256+tid (linear dest). Source chunk is the swizzled one for that slot.
  const int row0 = tid >> 2,         kc0 = tid & 3;
  const int row1 = 64 + row0,        kc1 = kc0;        // (256+tid)>>2, (256+tid)&3
  const int sw0 = (row0 >> 1) & 3;                     // == sw1 (row1 = row0+64)
  const int kg0 = kc0 ^ sw0;
  const int kg1 = kc1 ^ sw0;

  auto STAGE = [&](int buf, int kt) {
    const int k0 = kt << 5;
    gld_lds16(Aact + (size_t)(m0 + row0) * K + k0 + kg0 * 8,
              (const char*)sA[buf] + wbase * 16);
    gld_lds16(Bw   + (size_t)(n0 + row0) * K + k0 + kg0 * 8,
              (const char*)sB[buf] + wbase * 16);
    gld_lds16(Aact + (size_t)(m0 + row1) * K + k0 + kg1 * 8,
              (const char*)sA[buf] + (256 + wbase) * 16);
    gld_lds16(Bw   + (size_t)(n0 + row1) * K + k0 + kg1 * 8,
              (const char*)sB[buf] + (256 + wbase) * 16);
  };

  STAGE(0, 0);
  if (nk > 1) STAGE(1, 1);

  const int swr = (r16 >> 1) & 3;          // read-side swizzle, uniform over i
  const int qsw = (quad ^ swr) * 8;        // element offset of my 16B chunk

  for (int kt = 0; kt < nk; ++kt) {
    if (kt + 2 < nk) {
      STAGE((kt + 2) & 3, kt + 2);
      // 12 outstanding; wait until <=8 -> the 4 oldest (tile kt) have landed
      asm volatile("s_waitcnt vmcnt(8)" ::: "memory");
    } else if (kt + 1 < nk) {
      asm volatile("s_waitcnt vmcnt(4)" ::: "memory");
    } else {
      asm volatile("s_waitcnt vmcnt(0)" ::: "memory");
    }
    __builtin_amdgcn_s_barrier();       // all waves' tile-kt stages complete
    asm volatile("" ::: "memory");      // no LDS reads hoisted above barrier

    const unsigned short* a_s = sA[kt & 3];
    const unsigned short* b_s = sB[kt & 3];
    bf16x8 af[4], bfr[4];
#pragma unroll
    for (int i = 0; i < 4; ++i) {
      af[i]  = *(const bf16x8*)(a_s + (wm * 64 + i * 16 + r16) * 32 + qsw);
      bfr[i] = *(const bf16x8*)(b_s + (wn * 64 + i * 16 + r16) * 32 + qsw);
    }
#pragma unroll
    for (int i = 0; i < 4; ++i)
#pragma unroll
      for (int j = 0; j < 4; ++j)
        acc[i][j] = __builtin_amdgcn_mfma_f32_16x16x32_bf16(af[i], bfr[j], acc[i][j], 0, 0, 0);
    // no trailing barrier: next write of buf[kt&3] is STAGE(kt+4), two
    // barriers away; wave skew is bounded to one barrier interval.
  }

#pragma unroll
  for (int i = 0; i < 4; ++i) {
    const int ar = m0 + wm * 64 + i * 16 + quad * 4;
#pragma unroll
    for (int j = 0; j < 4; ++j) {
      const int cc = n0 + wn * 64 + j * 16 + r16;
#pragma unroll
      for (int r = 0; r < 4; ++r) {
        const size_t idx = (size_t)(ar + r) * M + cc;
        const float v = acc[i][j][r];
        if constexpr (EPI == EP_NONE)   Co[idx] = v;
        if constexpr (EPI == EP_SIG)    Co[idx] = 1.f / (1.f + __expf(-v));
        if constexpr (EPI == EP_RELUSQ) { const float t = fmaxf(v, 0.f); Cb[idx] = f2bf(t * t); }
        if constexpr (EPI == EP_ADD)    Co[idx] += v;
        if constexpr (EPI == EP_MULADD) Co[idx] += aux[idx] * v;
        if constexpr (EPI == EP_KVR) {
          Co[idx] = (blockIdx.z == 2) ? (1.f / (1.f + __expf(-v))) : v;
        }
      }
    }
  }
}

// LayerNorm over H=1024; optional embedding gather when ids != nullptr.
__global__ __launch_bounds__(256) void ln_kernel(
    const float* __restrict__ in, const int* __restrict__ ids,
    const float* __restrict__ emb,
    const float* __restrict__ gw, const float* __restrict__ gb,
    float* __restrict__ out)
{
  const int n = blockIdx.x, tid = threadIdx.x;
  const float* src = ids ? (emb + (size_t)ids[n] * HD) : (in + (size_t)n * HD);
  const float4 v = ((const float4*)src)[tid];
  float s  = v.x + v.y + v.z + v.w;
  float s2 = v.x * v.x + v.y * v.y + v.z * v.z + v.w * v.w;
#pragma unroll
  for (int off = 32; off > 0; off >>= 1) {
    s  += __shfl_down(s, off);
    s2 += __shfl_down(s2, off);
  }
  __shared__ float red[8];
  const int wv = tid >> 6, ln = tid & 63;
  if (ln == 0) { red[wv] = s; red[4 + wv] = s2; }
  __syncthreads();
  if (tid == 0) {
    const float S  = red[0] + red[1] + red[2] + red[3];
    const float S2 = red[4] + red[5] + red[6] + red[7];
    const float mu = S * (1.f / HD);
    const float var = S2 * (1.f / HD) - mu * mu;
    red[0] = mu; red[1] = rsqrtf(var + EPSF);
  }
  __syncthreads();
  const float mu = red[0], rs = red[1];
  const float4 w4 = ((const float4*)gw)[tid];
  const float4 b4 = ((const float4*)gb)[tid];
  float4 o;
  o.x = (v.x - mu) * rs * w4.x + b4.x;
  o.y = (v.y - mu) * rs * w4.y + b4.y;
  o.z = (v.z - mu) * rs * w4.z + b4.z;
  o.w = (v.w - mu) * rs * w4.w + b4.w;
  ((float4*)(out + (size_t)n * HD))[tid] = o;
}

// Fused LayerNorm + token-shift mix: per token n, LN(h[n]) and LN(h[n-1])
// computed in-register (prev is zero at t==0), then m*x + (1-m)*prev -> bf16.
__global__ __launch_bounds__(256) void lnmix_kernel(
    const float* __restrict__ h,
    const float* __restrict__ gw, const float* __restrict__ gb,
    const float* __restrict__ m0p, const float* __restrict__ m1p, const float* __restrict__ m2p,
    ushort4* __restrict__ o0, ushort4* __restrict__ o1, ushort4* __restrict__ o2)
{
  const int n = blockIdx.x, tid = threadIdx.x;
  const int t = n & (TT - 1);
  const float4 vc = ((const float4*)(h + (size_t)n * HD))[tid];
  float4 vp = make_float4(0.f, 0.f, 0.f, 0.f);
  if (t != 0) vp = ((const float4*)(h + (size_t)(n - 1) * HD))[tid];

  float sc  = vc.x + vc.y + vc.z + vc.w;
  float sc2 = vc.x * vc.x + vc.y * vc.y + vc.z * vc.z + vc.w * vc.w;
  float sp  = vp.x + vp.y + vp.z + vp.w;
  float sp2 = vp.x * vp.x + vp.y * vp.y + vp.z * vp.z + vp.w * vp.w;
#pragma unroll
  for (int off = 32; off > 0; off >>= 1) {
    sc  += __shfl_down(sc, off);
    sc2 += __shfl_down(sc2, off);
    sp  += __shfl_down(sp, off);
    sp2 += __shfl_down(sp2, off);
  }
  __shared__ float red[16];
  const int wv = tid >> 6, ln = tid & 63;
  if (ln == 0) { red[wv] = sc; red[4 + wv] = sc2; red[8 + wv] = sp; red[12 + wv] = sp2; }
  __syncthreads();
  if (tid == 0) {
    float S  = red[0] + red[1] + red[2] + red[3];
    float S2 = red[4] + red[5] + red[6] + red[7];
    float mu = S * (1.f / HD);
    float var = S2 * (1.f / HD) - mu * mu;
    red[0] = mu; red[1] = rsqrtf(var + EPSF);
    S  = red[8] + red[9] + red[10] + red[11];
    S2 = red[12] + red[13] + red[14] + red[15];
    mu = S * (1.f / HD);
    var = S2 * (1.f / HD) - mu * mu;
    red[2] = mu; red[3] = rsqrtf(var + EPSF);
  }
  __syncthreads();
  const float muc = red[0], rsc = red[1];
  const float mup = red[2], rsp = red[3];
  const float4 w4 = ((const float4*)gw)[tid];
  const float4 b4 = ((const float4*)gb)[tid];
  float4 xc, xp;
  xc.x = (vc.x - muc) * rsc * w4.x + b4.x;
  xc.y = (vc.y - muc) * rsc * w4.y + b4.y;
  xc.z = (vc.z - muc) * rsc * w4.z + b4.z;
  xc.w = (vc.w - muc) * rsc * w4.w + b4.w;
  if (t != 0) {
    xp.x = (vp.x - mup) * rsp * w4.x + b4.x;
    xp.y = (vp.y - mup) * rsp * w4.y + b4.y;
    xp.z = (vp.z - mup) * rsp * w4.z + b4.z;
    xp.w = (vp.w - mup) * rsp * w4.w + b4.w;
  } else {
    xp = make_float4(0.f, 0.f, 0.f, 0.f);
  }

  const size_t o = (size_t)n * 256 + tid;
  float4 m = ((const float4*)m0p)[tid];
  ushort4 r;
  r.x = f2bf(m.x * xc.x + (1.f - m.x) * xp.x);
  r.y = f2bf(m.y * xc.y + (1.f - m.y) * xp.y);
  r.z = f2bf(m.z * xc.z + (1.f - m.z) * xp.z);
  r.w = f2bf(m.w * xc.w + (1.f - m.w) * xp.w);
  o0[o] = r;
  m = ((const float4*)m1p)[tid];
  r.x = f2bf(m.x * xc.x + (1.f - m.x) * xp.x);
  r.y = f2bf(m.y * xc.y + (1.f - m.y) * xp.y);
  r.z = f2bf(m.z * xc.z + (1.f - m.z) * xp.z);
  r.w = f2bf(m.w * xc.w + (1.f - m.w) * xp.w);
  o1[o] = r;
  if (o2) {
    m = ((const float4*)m2p)[tid];
    r.x = f2bf(m.x * xc.x + (1.f - m.x) * xp.x);
    r.y = f2bf(m.y * xc.y + (1.f - m.y) * xp.y);
    r.z = f2bf(m.z * xc.z + (1.f - m.z) * xp.z);
    r.w = f2bf(m.w * xc.w + (1.f - m.w) * xp.w);
    o2[o] = r;
  }
}

// ---- blocked WKV ----
// channel c = b*AD + a.  k/v/r layout: [(b*TT + t) * AD + a].
// Phase 1: per (channel, chunk) local transform (la, lb, lp) from zero init.
__global__ __launch_bounds__(256) void wkv_p1(
    const float* __restrict__ kx, const float* __restrict__ vx,
    const float* __restrict__ tdecay,
    float* __restrict__ la, float* __restrict__ lb, float* __restrict__ lp)
{
  const int c = blockIdx.x * 256 + threadIdx.x;
  const int a = c & (AD - 1);
  const int b = c >> 10;
  const int j = blockIdx.y;
  const float w = -__expf(tdecay[a]);
  const size_t base = ((size_t)b * TT + (size_t)j * WKV_C) * AD + a;
  float A = 0.f, Bb = 0.f, p = NEGF;
#pragma unroll 4
  for (int t = 0; t < WKV_C; ++t) {
    const float kt = kx[base + (size_t)t * AD];
    const float vt = vx[base + (size_t)t * AD];
    const float pn = fmaxf(p + w, kt);
    const float s1 = __expf(p + w - pn);
    const float s2 = __expf(kt - pn);
    A = s1 * A + s2 * vt;
    Bb = s1 * Bb + s2;
    p = pn;
  }
  const int o = j * NCH + c;
  la[o] = A; lb[o] = Bb; lp[o] = p;
}

// Phase 2: per channel, exclusive prefix combine over chunks.
__global__ __launch_bounds__(256) void wkv_p2(
    const float* __restrict__ la, const float* __restrict__ lb,
    const float* __restrict__ lp, const float* __restrict__ tdecay,
    float* __restrict__ sa, float* __restrict__ sb, float* __restrict__ sp)
{
  const int c = blockIdx.x * 256 + threadIdx.x;
  const int a = c & (AD - 1);
  const float wC = -__expf(tdecay[a]) * (float)WKV_C;
  float A = 0.f, Bb = 0.f, p = NEGF;
  for (int j = 0; j < WKV_NC; ++j) {
    const int o = j * NCH + c;
    sa[o] = A; sb[o] = Bb; sp[o] = p;
    const float A2 = la[o], B2 = lb[o], p2 = lp[o];
    const float pn = fmaxf(p + wC, p2);
    const float e1 = __expf(p + wC - pn);
    const float e2 = __expf(p2 - pn);
    A = e1 * A + e2 * A2;
    Bb = e1 * Bb + e2 * B2;
    p = pn;
  }
}

// Phase 3: re-run reference step per chunk from incoming state; fused r*y -> bf16.
__global__ __launch_bounds__(256) void wkv_p3(
    const float* __restrict__ kx, const float* __restrict__ vx,
    const float* __restrict__ rx,
    const float* __restrict__ tfirst, const float* __restrict__ tdecay,
    const float* __restrict__ sa, const float* __restrict__ sb,
    const float* __restrict__ sp,
    unsigned short* __restrict__ ry)
{
  const int c = blockIdx.x * 256 + threadIdx.x;
  const int a = c & (AD - 1);
  const int b = c >> 10;
  const int j = blockIdx.y;
  const float u = tfirst[a];
  const float w = -__expf(tdecay[a]);
  const size_t base = ((size_t)b * TT + (size_t)j * WKV_C) * AD + a;
  const int o = j * NCH + c;
  float A = sa[o], Bb = sb[o], p = sp[o];
#pragma unroll 2
  for (int t = 0; t < WKV_C; ++t) {
    const size_t off = base + (size_t)t * AD;
    const float kt = kx[off], vt = vx[off];
    const float q  = fmaxf(p, u + kt);
    const float wt = __expf(u + kt - q);
    const float sc = __expf(p - q);
    const float y  = (A * sc + wt * vt) / (Bb * sc + wt);
    ry[off] = f2bf(y * rx[off]);
    const float pn = fmaxf(p + w, kt);
    const float s1 = __expf(p + w - pn);
    const float s2 = __expf(kt - pn);
    A = s1 * A + s2 * vt;
    Bb = s1 * Bb + s2;
    p = pn;
  }
}

// One-shot per-layer weight cast: 7 tensors -> bf16 packed into wb.
// Ranges (in float4/ushort4 units) are laid out so dst index == global index.
__global__ __launch_bounds__(256) void f2b7_kernel(
    const float* __restrict__ s0, const float* __restrict__ s1,
    const float* __restrict__ s2, const float* __restrict__ s3,
    const float* __restrict__ s4, const float* __restrict__ s5,
    const float* __restrict__ s6, ushort4* __restrict__ wb4)
{
  const size_t i = (size_t)blockIdx.x * 256 + threadIdx.x;  // < 3407872
  const float* s; size_t rel;
  if      (i <  262144) { s = s0; rel = i; }
  else if (i <  524288) { s = s1; rel = i -  262144; }
  else if (i <  786432) { s = s2; rel = i -  524288; }
  else if (i < 1048576) { s = s3; rel = i -  786432; }
  else if (i < 2097152) { s = s4; rel = i - 1048576; }
  else if (i < 2359296) { s = s5; rel = i - 2097152; }
  else                  { s = s6; rel = i - 2359296; }
  const float4 v = ((const float4*)s)[rel];
  ushort4 r;
  r.x = f2bf(v.x); r.y = f2bf(v.y); r.z = f2bf(v.z); r.w = f2bf(v.w);
  wb4[i] = r;
}

extern "C" void kernel_launch(void* const* d_in, const int* in_sizes, int n_in,
                              void* d_out, int out_size, void* d_ws, size_t ws_size,
                              hipStream_t stream)
{
  (void)in_sizes; (void)n_in; (void)out_size; (void)ws_size;
  const int*   ids   = (const int*)d_in[0];
  const float* emb   = (const float*)d_in[1];
  const float* prew  = (const float*)d_in[2];
  const float* preb  = (const float*)d_in[3];
  const float* postw = (const float*)d_in[4];
  const float* postb = (const float*)d_in[5];
  const float* ln1w  = (const float*)d_in[6];
  const float* ln1b  = (const float*)d_in[7];
  const float* ln2w  = (const float*)d_in[8];
  const float* ln2b  = (const float*)d_in[9];
  const float* amk   = (const float*)d_in[10];
  const float* amv   = (const float*)d_in[11];
  const float* amr   = (const float*)d_in[12];
  const float* awk   = (const float*)d_in[13];
  const float* awv   = (const float*)d_in[14];
  const float* awr   = (const float*)d_in[15];
  const float* awo   = (const float*)d_in[16];
  const float* td    = (const float*)d_in[17];
  const float* tf    = (const float*)d_in[18];
  const float* fmk   = (const float*)d_in[19];
  const float* fmr   = (const float*)d_in[20];
  const float* fwk   = (const float*)d_in[21];
  const float* fwr   = (const float*)d_in[22];
  const float* fwv   = (const float*)d_in[23];

  char* ws = (char*)d_ws;
  float* h  = (float*)(ws + 0);                         // 32MB fp32 [8192,1024]
  float* x  = (float*)(ws + 33554432);                  // 32MB fp32 (WKV scratch)
  float* kb = (float*)(ws + 67108864);                  // 32MB fp32  (kb,vb,rb contiguous)
  float* vb = (float*)(ws + 100663296);                 // 32MB fp32
  float* rb = (float*)(ws + 134217728);                 // 32MB fp32
  unsigned short* ab = (unsigned short*)(ws + 167772160); // 64MB bf16 [8192,4096]
  unsigned short* wb = (unsigned short*)(ws + 234881024); // 27MB bf16 per-layer weights

  unsigned short* xk = ab;                              // xk,xv,xr contiguous (stride 8388608)
  unsigned short* xv = ab + 8388608;
  unsigned short* xr = ab + 16777216;
  unsigned short* ry = ab + 25165824;

  // WKV scratch lives in x (free during attention's WKV): 6 x NC*NCH floats = 6MB
  float* wla = x;
  float* wlb = x + WKV_NC * NCH;
  float* wlp = x + 2 * WKV_NC * NCH;
  float* wsa = x + 3 * WKV_NC * NCH;
  float* wsb = x + 4 * WKV_NC * NCH;
  float* wsp = x + 5 * WKV_NC * NCH;

  const dim3 blk(256);
  const dim3 g1(NTOK / 128, 1024 / 128);
  const dim3 g2(NTOK / 128, 4096 / 128);
  const dim3 gkvr(NTOK / 128, 1024 / 128, 3);
  const dim3 gw(NCH / 256, WKV_NC);

  ln_kernel<<<NTOK, blk, 0, stream>>>(nullptr, ids, emb, prew, preb, h);

  for (int i = 0; i < LNUM; ++i) {
    // per-layer weights -> bf16, one launch
    f2b7_kernel<<<13312, blk, 0, stream>>>(
        awk + (size_t)i * 1048576, awv + (size_t)i * 1048576,
        awr + (size_t)i * 1048576, awo + (size_t)i * 1048576,
        fwk + (size_t)i * 4194304, fwr + (size_t)i * 1048576,
        fwv + (size_t)i * 4194304, (ushort4*)wb);

    // attention
    lnmix_kernel<<<NTOK, blk, 0, stream>>>(h, ln1w + i * HD, ln1b + i * HD,
                                           amk + i * HD, amv + i * HD, amr + i * HD,
                                           (ushort4*)xk, (ushort4*)xv, (ushort4*)xr);
    gemm_nt<EP_KVR><<<gkvr, blk, 0, stream>>>(xk, wb, kb, nullptr, nullptr, 1024, 1024);
    wkv_p1<<<gw, blk, 0, stream>>>(kb, vb, td + i * AD, wla, wlb, wlp);
    wkv_p2<<<NCH / 256, blk, 0, stream>>>(wla, wlb, wlp, td + i * AD, wsa, wsb, wsp);
    wkv_p3<<<gw, blk, 0, stream>>>(kb, vb, rb, tf + i * AD, td + i * AD, wsa, wsb, wsp, ry);
    gemm_nt<EP_ADD ><<<g1, blk, 0, stream>>>(ry, wb + 3145728, h, nullptr, nullptr, 1024, 1024);

    // ffn
    lnmix_kernel<<<NTOK, blk, 0, stream>>>(h, ln2w + i * HD, ln2b + i * HD,
                                           fmk + i * HD, fmr + i * HD, nullptr,
                                           (ushort4*)kb, (ushort4*)vb, nullptr);
    gemm_nt<EP_RELUSQ><<<g2, blk, 0, stream>>>((unsigned short*)kb, wb + 4194304, nullptr, ab, nullptr, 1024, 4096);
    gemm_nt<EP_SIG   ><<<g1, blk, 0, stream>>>((unsigned short*)vb, wb + 8388608, rb, nullptr, nullptr, 1024, 1024);
    gemm_nt<EP_MULADD><<<g1, blk, 0, stream>>>(ab, wb + 9437184, h, nullptr, rb, 4096, 1024);
  }

  ln_kernel<<<NTOK, blk, 0, stream>>>(h, nullptr, nullptr, postw, postb, (float*)d_out);
}

// Round 4
// 2692.928 us; speedup vs baseline: 1.2921x; 1.0213x over previous
//
#include <hip/hip_runtime.h>
#include <stdint.h>

// RWKV forward, MI355X. Round 5 (resubmit — prior bench was an infra failure):
// 8-wave (512-thread) GEMM blocks — same 128^2 tile, 4-buffer counted-vmcnt
// pipeline, T2 swizzle — doubling waves/CU from 8 to 16 (grid/LDS cap blocks
// at 2/CU; waves were the structural limiter). Each wave owns a 64x32
// sub-tile (2m x 4n waves, acc 4x2). Also fused the two independent FFN GEMMs
// (fk + fr) into one launch via blockIdx.y.

#define LNUM 6
#define HD   1024
#define AD   1024
#define TT   2048
#define NTOK 8192
#define EPSF 1e-5f
#define NEGF (-1e38f)

#define WKV_C  32            // chunk length
#define WKV_NC 64            // chunks per channel (WKV_C * WKV_NC == TT)
#define NCH    4096          // B * A channels

typedef __attribute__((ext_vector_type(8))) short bf16x8;
typedef __attribute__((ext_vector_type(4))) float f32x4;

__device__ __forceinline__ unsigned short f2bf(float f) {
  union { float f; uint32_t u; } c; c.f = f;
  uint32_t r = c.u + 0x7fffu + ((c.u >> 16) & 1u);
  return (unsigned short)(r >> 16);
}

// async global->LDS, 16B per lane; lds dest must be wave-uniform base (+lane*16 implicit)
__device__ __forceinline__ void gld_lds16(const void* g, const void* l) {
  __builtin_amdgcn_global_load_lds(
      (const __attribute__((address_space(1))) void*)(uintptr_t)g,
      (__attribute__((address_space(3))) void*)(uint32_t)(uintptr_t)l,
      16, 0, 0);
}

enum { EP_NONE = 0, EP_SIG = 1, EP_RELUSQ = 2, EP_ADD = 3, EP_MULADD = 4,
       EP_KVR = 5, EP_FKR = 6 };

// C[n,m] = sum_k A[n,k]*B[m,k]; A:[NTOK,K] bf16 row-major, B:[M,K] bf16 row-major.
// 8 waves (512 thr), 128x128 tile, 4 LDS buffers; STAGE(t+2) at iter top;
// counted vmcnt(4) keeps 2 tiles in flight across the single raw barrier.
// T2 swizzle: row's four 16B chunks permuted by kc^((row>>1)&3) on the GLOBAL
// source (LDS dest linear, required by global_load_lds) and on the ds_read
// offset -> quarter-wave b128 reads spread 2-way over all 8 bank-quads (free).
// EP_KVR: blockIdx.z in {0,1,2} selects xk/xv/xr vs wk/wv/wr vs kb/vb/rb;
//         z==2 applies sigmoid.
// EP_FKR: blockIdx.y<32 -> ffn_k GEMM (RELUSQ->bf16 Cb, M=4096);
//         y>=32 -> ffn_r GEMM (SIG->f32 Co, M=1024, A/B at fixed offsets).
template <int EPI>
__global__ __launch_bounds__(512, 4) void gemm_nt(
    const unsigned short* __restrict__ Aact,
    const unsigned short* __restrict__ Bw,
    float* __restrict__ Co,
    unsigned short* __restrict__ Cb,
    const float* __restrict__ aux,
    int K, int M)
{
  __shared__ unsigned short sA[4][128 * 32];
  __shared__ unsigned short sB[4][128 * 32];
  const int tid  = threadIdx.x;
  const int lane = tid & 63;
  const int wave = tid >> 6;
  const int quad = lane >> 4;
  const int r16  = lane & 15;
  const int wm = wave >> 2, wn = wave & 3;       // 2 x 4 waves, 64x32 each
  const int m0 = blockIdx.x * 128;               // activation rows
  int n0 = blockIdx.y * 128;                     // weight rows (output cols)

  bool sig = false;
  if constexpr (EPI == EP_KVR) {
    const int z = blockIdx.z;
    Aact += (size_t)z * 8388608;     // xk/xv/xr, each [8192,1024] bf16
    Bw   += (size_t)z * 1048576;     // wk/wv/wr, each [1024,1024] bf16
    Co   += (size_t)z * 8388608;     // kb/vb/rb, each [8192,1024] f32
  }
  if constexpr (EPI == EP_FKR) {
    if (blockIdx.y >= 32) {          // ffn_r
      sig = true;
      Aact += 16777216;              // xr2 (bf16, staged in vb)
      Bw   += 4194304;               // fwr follows fwk in wb
      n0   = (blockIdx.y - 32) * 128;
      M    = 1024;
    } else {
      M = 4096;
    }
  }

  f32x4 acc[4][2];
#pragma unroll
  for (int i = 0; i < 4; ++i)
#pragma unroll
    for (int j = 0; j < 2; ++j) acc[i][j] = (f32x4){0.f, 0.f, 0.f, 0.f};

  const int nk = K >> 5;

  // staging: 512 x 16B chunks per tile per matrix; thread owns chunk tid.
  const int row0 = tid >> 2, kc0 = tid & 3;
  const int kg0  = kc0 ^ ((row0 >> 1) & 3);      // swizzled source chunk
  const int wbase = wave * 64 * 16;              // wave-uniform LDS byte base

  auto STAGE = [&](int buf, int kt) {
    const int k0 = kt << 5;
    gld_lds16(Aact + (size_t)(m0 + row0) * K + k0 + kg0 * 8,
              (const char*)sA[buf] + wbase);
    gld_lds16(Bw   + (size_t)(n0 + row0) * K + k0 + kg0 * 8,
              (const char*)sB[buf] + wbase);
  };

  STAGE(0, 0);
  if (nk > 1) STAGE(1, 1);

  const int qsw = (quad ^ ((r16 >> 1) & 3)) * 8; // read-side swizzle

  for (int kt = 0; kt < nk; ++kt) {
    if (kt + 2 < nk) {
      STAGE((kt + 2) & 3, kt + 2);
      // 6 outstanding; wait until <=4 -> the 2 oldest (tile kt) have landed
      asm volatile("s_waitcnt vmcnt(4)" ::: "memory");
    } else if (kt + 1 < nk) {
      asm volatile("s_waitcnt vmcnt(2)" ::: "memory");
    } else {
      asm volatile("s_waitcnt vmcnt(0)" ::: "memory");
    }
    __builtin_amdgcn_s_barrier();       // all waves' tile-kt stages complete
    asm volatile("" ::: "memory");      // no LDS reads hoisted above barrier

    const unsigned short* a_s = sA[kt & 3];
    const unsigned short* b_s = sB[kt & 3];
    bf16x8 af[4], bfr[2];
#pragma unroll
    for (int i = 0; i < 4; ++i)
      af[i]  = *(const bf16x8*)(a_s + (wm * 64 + i * 16 + r16) * 32 + qsw);
#pragma unroll
    for (int j = 0; j < 2; ++j)
      bfr[j] = *(const bf16x8*)(b_s + (wn * 32 + j * 16 + r16) * 32 + qsw);
#pragma unroll
    for (int i = 0; i < 4; ++i)
#pragma unroll
      for (int j = 0; j < 2; ++j)
        acc[i][j] = __builtin_amdgcn_mfma_f32_16x16x32_bf16(af[i], bfr[j], acc[i][j], 0, 0, 0);
    // no trailing barrier: next write of buf[kt&3] is STAGE(kt+4), two
    // barriers away; wave skew is bounded to one barrier interval.
  }

#pragma unroll
  for (int i = 0; i < 4; ++i) {
    const int ar = m0 + wm * 64 + i * 16 + quad * 4;
#pragma unroll
    for (int j = 0; j < 2; ++j) {
      const int cc = n0 + wn * 32 + j * 16 + r16;
#pragma unroll
      for (int r = 0; r < 4; ++r) {
        const size_t idx = (size_t)(ar + r) * M + cc;
        const float v = acc[i][j][r];
        if constexpr (EPI == EP_NONE)   Co[idx] = v;
        if constexpr (EPI == EP_SIG)    Co[idx] = 1.f / (1.f + __expf(-v));
        if constexpr (EPI == EP_RELUSQ) { const float t = fmaxf(v, 0.f); Cb[idx] = f2bf(t * t); }
        if constexpr (EPI == EP_ADD)    Co[idx] += v;
        if constexpr (EPI == EP_MULADD) Co[idx] += aux[idx] * v;
        if constexpr (EPI == EP_KVR)
          Co[idx] = (blockIdx.z == 2) ? (1.f / (1.f + __expf(-v))) : v;
        if constexpr (EPI == EP_FKR) {
          if (sig) Co[idx] = 1.f / (1.f + __expf(-v));
          else     { const float t = fmaxf(v, 0.f); Cb[idx] = f2bf(t * t); }
        }
      }
    }
  }
}

// LayerNorm over H=1024; optional embedding gather when ids != nullptr.
__global__ __launch_bounds__(256) void ln_kernel(
    const float* __restrict__ in, const int* __restrict__ ids,
    const float* __restrict__ emb,
    const float* __restrict__ gw, const float* __restrict__ gb,
    float* __restrict__ out)
{
  const int n = blockIdx.x, tid = threadIdx.x;
  const float* src = ids ? (emb + (size_t)ids[n] * HD) : (in + (size_t)n * HD);
  const float4 v = ((const float4*)src)[tid];
  float s  = v.x + v.y + v.z + v.w;
  float s2 = v.x * v.x + v.y * v.y + v.z * v.z + v.w * v.w;
#pragma unroll
  for (int off = 32; off > 0; off >>= 1) {
    s  += __shfl_down(s, off);
    s2 += __shfl_down(s2, off);
  }
  __shared__ float red[8];
  const int wv = tid >> 6, ln = tid & 63;
  if (ln == 0) { red[wv] = s; red[4 + wv] = s2; }
  __syncthreads();
  if (tid == 0) {
    const float S  = red[0] + red[1] + red[2] + red[3];
    const float S2 = red[4] + red[5] + red[6] + red[7];
    const float mu = S * (1.f / HD);
    const float var = S2 * (1.f / HD) - mu * mu;
    red[0] = mu; red[1] = rsqrtf(var + EPSF);
  }
  __syncthreads();
  const float mu = red[0], rs = red[1];
  const float4 w4 = ((const float4*)gw)[tid];
  const float4 b4 = ((const float4*)gb)[tid];
  float4 o;
  o.x = (v.x - mu) * rs * w4.x + b4.x;
  o.y = (v.y - mu) * rs * w4.y + b4.y;
  o.z = (v.z - mu) * rs * w4.z + b4.z;
  o.w = (v.w - mu) * rs * w4.w + b4.w;
  ((float4*)(out + (size_t)n * HD))[tid] = o;
}

// Fused LayerNorm + token-shift mix: per token n, LN(h[n]) and LN(h[n-1])
// computed in-register (prev is zero at t==0), then m*x + (1-m)*prev -> bf16.
__global__ __launch_bounds__(256) void lnmix_kernel(
    const float* __restrict__ h,
    const float* __restrict__ gw, const float* __restrict__ gb,
    const float* __restrict__ m0p, const float* __restrict__ m1p, const float* __restrict__ m2p,
    ushort4* __restrict__ o0, ushort4* __restrict__ o1, ushort4* __restrict__ o2)
{
  const int n = blockIdx.x, tid = threadIdx.x;
  const int t = n & (TT - 1);
  const float4 vc = ((const float4*)(h + (size_t)n * HD))[tid];
  float4 vp = make_float4(0.f, 0.f, 0.f, 0.f);
  if (t != 0) vp = ((const float4*)(h + (size_t)(n - 1) * HD))[tid];

  float sc  = vc.x + vc.y + vc.z + vc.w;
  float sc2 = vc.x * vc.x + vc.y * vc.y + vc.z * vc.z + vc.w * vc.w;
  float sp  = vp.x + vp.y + vp.z + vp.w;
  float sp2 = vp.x * vp.x + vp.y * vp.y + vp.z * vp.z + vp.w * vp.w;
#pragma unroll
  for (int off = 32; off > 0; off >>= 1) {
    sc  += __shfl_down(sc, off);
    sc2 += __shfl_down(sc2, off);
    sp  += __shfl_down(sp, off);
    sp2 += __shfl_down(sp2, off);
  }
  __shared__ float red[16];
  const int wv = tid >> 6, ln = tid & 63;
  if (ln == 0) { red[wv] = sc; red[4 + wv] = sc2; red[8 + wv] = sp; red[12 + wv] = sp2; }
  __syncthreads();
  if (tid == 0) {
    float S  = red[0] + red[1] + red[2] + red[3];
    float S2 = red[4] + red[5] + red[6] + red[7];
    float mu = S * (1.f / HD);
    float var = S2 * (1.f / HD) - mu * mu;
    red[0] = mu; red[1] = rsqrtf(var + EPSF);
    S  = red[8] + red[9] + red[10] + red[11];
    S2 = red[12] + red[13] + red[14] + red[15];
    mu = S * (1.f / HD);
    var = S2 * (1.f / HD) - mu * mu;
    red[2] = mu; red[3] = rsqrtf(var + EPSF);
  }
  __syncthreads();
  const float muc = red[0], rsc = red[1];
  const float mup = red[2], rsp = red[3];
  const float4 w4 = ((const float4*)gw)[tid];
  const float4 b4 = ((const float4*)gb)[tid];
  float4 xc, xp;
  xc.x = (vc.x - muc) * rsc * w4.x + b4.x;
  xc.y = (vc.y - muc) * rsc * w4.y + b4.y;
  xc.z = (vc.z - muc) * rsc * w4.z + b4.z;
  xc.w = (vc.w - muc) * rsc * w4.w + b4.w;
  if (t != 0) {
    xp.x = (vp.x - mup) * rsp * w4.x + b4.x;
    xp.y = (vp.y - mup) * rsp * w4.y + b4.y;
    xp.z = (vp.z - mup) * rsp * w4.z + b4.z;
    xp.w = (vp.w - mup) * rsp * w4.w + b4.w;
  } else {
    xp = make_float4(0.f, 0.f, 0.f, 0.f);
  }

  const size_t o = (size_t)n * 256 + tid;
  float4 m = ((const float4*)m0p)[tid];
  ushort4 r;
  r.x = f2bf(m.x * xc.x + (1.f - m.x) * xp.x);
  r.y = f2bf(m.y * xc.y + (1.f - m.y) * xp.y);
  r.z = f2bf(m.z * xc.z + (1.f - m.z) * xp.z);
  r.w = f2bf(m.w * xc.w + (1.f - m.w) * xp.w);
  o0[o] = r;
  m = ((const float4*)m1p)[tid];
  r.x = f2bf(m.x * xc.x + (1.f - m.x) * xp.x);
  r.y = f2bf(m.y * xc.y + (1.f - m.y) * xp.y);
  r.z = f2bf(m.z * xc.z + (1.f - m.z) * xp.z);
  r.w = f2bf(m.w * xc.w + (1.f - m.w) * xp.w);
  o1[o] = r;
  if (o2) {
    m = ((const float4*)m2p)[tid];
    r.x = f2bf(m.x * xc.x + (1.f - m.x) * xp.x);
    r.y = f2bf(m.y * xc.y + (1.f - m.y) * xp.y);
    r.z = f2bf(m.z * xc.z + (1.f - m.z) * xp.z);
    r.w = f2bf(m.w * xc.w + (1.f - m.w) * xp.w);
    o2[o] = r;
  }
}

// ---- blocked WKV ----
// channel c = b*AD + a.  k/v/r layout: [(b*TT + t) * AD + a].
// Phase 1: per (channel, chunk) local transform (la, lb, lp) from zero init.
__global__ __launch_bounds__(256) void wkv_p1(
    const float* __restrict__ kx, const float* __restrict__ vx,
    const float* __restrict__ tdecay,
    float* __restrict__ la, float* __restrict__ lb, float* __restrict__ lp)
{
  const int c = blockIdx.x * 256 + threadIdx.x;
  const int a = c & (AD - 1);
  const int b = c >> 10;
  const int j = blockIdx.y;
  const float w = -__expf(tdecay[a]);
  const size_t base = ((size_t)b * TT + (size_t)j * WKV_C) * AD + a;
  float A = 0.f, Bb = 0.f, p = NEGF;
#pragma unroll 4
  for (int t = 0; t < WKV_C; ++t) {
    const float kt = kx[base + (size_t)t * AD];
    const float vt = vx[base + (size_t)t * AD];
    const float pn = fmaxf(p + w, kt);
    const float s1 = __expf(p + w - pn);
    const float s2 = __expf(kt - pn);
    A = s1 * A + s2 * vt;
    Bb = s1 * Bb + s2;
    p = pn;
  }
  const int o = j * NCH + c;
  la[o] = A; lb[o] = Bb; lp[o] = p;
}

// Phase 2: per channel, exclusive prefix combine over chunks.
__global__ __launch_bounds__(256) void wkv_p2(
    const float* __restrict__ la, const float* __restrict__ lb,
    const float* __restrict__ lp, const float* __restrict__ tdecay,
    float* __restrict__ sa, float* __restrict__ sb, float* __restrict__ sp)
{
  const int c = blockIdx.x * 256 + threadIdx.x;
  const int a = c & (AD - 1);
  const float wC = -__expf(tdecay[a]) * (float)WKV_C;
  float A = 0.f, Bb = 0.f, p = NEGF;
  for (int j = 0; j < WKV_NC; ++j) {
    const int o = j * NCH + c;
    sa[o] = A; sb[o] = Bb; sp[o] = p;
    const float A2 = la[o], B2 = lb[o], p2 = lp[o];
    const float pn = fmaxf(p + wC, p2);
    const float e1 = __expf(p + wC - pn);
    const float e2 = __expf(p2 - pn);
    A = e1 * A + e2 * A2;
    Bb = e1 * Bb + e2 * B2;
    p = pn;
  }
}

// Phase 3: re-run reference step per chunk from incoming state; fused r*y -> bf16.
__global__ __launch_bounds__(256) void wkv_p3(
    const float* __restrict__ kx, const float* __restrict__ vx,
    const float* __restrict__ rx,
    const float* __restrict__ tfirst, const float* __restrict__ tdecay,
    const float* __restrict__ sa, const float* __restrict__ sb,
    const float* __restrict__ sp,
    unsigned short* __restrict__ ry)
{
  const int c = blockIdx.x * 256 + threadIdx.x;
  const int a = c & (AD - 1);
  const int b = c >> 10;
  const int j = blockIdx.y;
  const float u = tfirst[a];
  const float w = -__expf(tdecay[a]);
  const size_t base = ((size_t)b * TT + (size_t)j * WKV_C) * AD + a;
  const int o = j * NCH + c;
  float A = sa[o], Bb = sb[o], p = sp[o];
#pragma unroll 2
  for (int t = 0; t < WKV_C; ++t) {
    const size_t off = base + (size_t)t * AD;
    const float kt = kx[off], vt = vx[off];
    const float q  = fmaxf(p, u + kt);
    const float wt = __expf(u + kt - q);
    const float sc = __expf(p - q);
    const float y  = (A * sc + wt * vt) / (Bb * sc + wt);
    ry[off] = f2bf(y * rx[off]);
    const float pn = fmaxf(p + w, kt);
    const float s1 = __expf(p + w - pn);
    const float s2 = __expf(kt - pn);
    A = s1 * A + s2 * vt;
    Bb = s1 * Bb + s2;
    p = pn;
  }
}

// One-shot per-layer weight cast: 7 tensors -> bf16 packed into wb.
__global__ __launch_bounds__(256) void f2b7_kernel(
    const float* __restrict__ s0, const float* __restrict__ s1,
    const float* __restrict__ s2, const float* __restrict__ s3,
    const float* __restrict__ s4, const float* __restrict__ s5,
    const float* __restrict__ s6, ushort4* __restrict__ wb4)
{
  const size_t i = (size_t)blockIdx.x * 256 + threadIdx.x;  // < 3407872
  const float* s; size_t rel;
  if      (i <  262144) { s = s0; rel = i; }
  else if (i <  524288) { s = s1; rel = i -  262144; }
  else if (i <  786432) { s = s2; rel = i -  524288; }
  else if (i < 1048576) { s = s3; rel = i -  786432; }
  else if (i < 2097152) { s = s4; rel = i - 1048576; }
  else if (i < 2359296) { s = s5; rel = i - 2097152; }
  else                  { s = s6; rel = i - 2359296; }
  const float4 v = ((const float4*)s)[rel];
  ushort4 r;
  r.x = f2bf(v.x); r.y = f2bf(v.y); r.z = f2bf(v.z); r.w = f2bf(v.w);
  wb4[i] = r;
}

extern "C" void kernel_launch(void* const* d_in, const int* in_sizes, int n_in,
                              void* d_out, int out_size, void* d_ws, size_t ws_size,
                              hipStream_t stream)
{
  (void)in_sizes; (void)n_in; (void)out_size; (void)ws_size;
  const int*   ids   = (const int*)d_in[0];
  const float* emb   = (const float*)d_in[1];
  const float* prew  = (const float*)d_in[2];
  const float* preb  = (const float*)d_in[3];
  const float* postw = (const float*)d_in[4];
  const float* postb = (const float*)d_in[5];
  const float* ln1w  = (const float*)d_in[6];
  const float* ln1b  = (const float*)d_in[7];
  const float* ln2w  = (const float*)d_in[8];
  const float* ln2b  = (const float*)d_in[9];
  const float* amk   = (const float*)d_in[10];
  const float* amv   = (const float*)d_in[11];
  const float* amr   = (const float*)d_in[12];
  const float* awk   = (const float*)d_in[13];
  const float* awv   = (const float*)d_in[14];
  const float* awr   = (const float*)d_in[15];
  const float* awo   = (const float*)d_in[16];
  const float* td    = (const float*)d_in[17];
  const float* tf    = (const float*)d_in[18];
  const float* fmk   = (const float*)d_in[19];
  const float* fmr   = (const float*)d_in[20];
  const float* fwk   = (const float*)d_in[21];
  const float* fwr   = (const float*)d_in[22];
  const float* fwv   = (const float*)d_in[23];

  char* ws = (char*)d_ws;
  float* h  = (float*)(ws + 0);                         // 32MB fp32 [8192,1024]
  float* x  = (float*)(ws + 33554432);                  // 32MB fp32 (WKV scratch)
  float* kb = (float*)(ws + 67108864);                  // 32MB fp32  (kb,vb,rb contiguous)
  float* vb = (float*)(ws + 100663296);                 // 32MB fp32
  float* rb = (float*)(ws + 134217728);                 // 32MB fp32
  unsigned short* ab = (unsigned short*)(ws + 167772160); // 64MB bf16 [8192,4096]
  unsigned short* wb = (unsigned short*)(ws + 234881024); // 27MB bf16 per-layer weights

  unsigned short* xk = ab;                              // xk,xv,xr contiguous (stride 8388608)
  unsigned short* xv = ab + 8388608;
  unsigned short* xr = ab + 16777216;
  unsigned short* ry = ab + 25165824;

  // WKV scratch lives in x (free during attention's WKV): 6 x NC*NCH floats = 6MB
  float* wla = x;
  float* wlb = x + WKV_NC * NCH;
  float* wlp = x + 2 * WKV_NC * NCH;
  float* wsa = x + 3 * WKV_NC * NCH;
  float* wsb = x + 4 * WKV_NC * NCH;
  float* wsp = x + 5 * WKV_NC * NCH;

  const dim3 blk(256);
  const dim3 gblk(512);
  const dim3 g1(NTOK / 128, 1024 / 128);
  const dim3 gkvr(NTOK / 128, 1024 / 128, 3);
  const dim3 gffn(NTOK / 128, 40);                      // y<32: fk(M=4096); y>=32: fr(M=1024)
  const dim3 gw(NCH / 256, WKV_NC);

  ln_kernel<<<NTOK, blk, 0, stream>>>(nullptr, ids, emb, prew, preb, h);

  for (int i = 0; i < LNUM; ++i) {
    // per-layer weights -> bf16, one launch
    f2b7_kernel<<<13312, blk, 0, stream>>>(
        awk + (size_t)i * 1048576, awv + (size_t)i * 1048576,
        awr + (size_t)i * 1048576, awo + (size_t)i * 1048576,
        fwk + (size_t)i * 4194304, fwr + (size_t)i * 1048576,
        fwv + (size_t)i * 4194304, (ushort4*)wb);

    // attention
    lnmix_kernel<<<NTOK, blk, 0, stream>>>(h, ln1w + i * HD, ln1b + i * HD,
                                           amk + i * HD, amv + i * HD, amr + i * HD,
                                           (ushort4*)xk, (ushort4*)xv, (ushort4*)xr);
    gemm_nt<EP_KVR><<<gkvr, gblk, 0, stream>>>(xk, wb, kb, nullptr, nullptr, 1024, 1024);
    wkv_p1<<<gw, blk, 0, stream>>>(kb, vb, td + i * AD, wla, wlb, wlp);
    wkv_p2<<<NCH / 256, blk, 0, stream>>>(wla, wlb, wlp, td + i * AD, wsa, wsb, wsp);
    wkv_p3<<<gw, blk, 0, stream>>>(kb, vb, rb, tf + i * AD, td + i * AD, wsa, wsb, wsp, ry);
    gemm_nt<EP_ADD ><<<g1, gblk, 0, stream>>>(ry, wb + 3145728, h, nullptr, nullptr, 1024, 1024);

    // ffn: fused fk (RELUSQ -> ab) + fr (SIG -> rb) in one launch
    lnmix_kernel<<<NTOK, blk, 0, stream>>>(h, ln2w + i * HD, ln2b + i * HD,
                                           fmk + i * HD, fmr + i * HD, nullptr,
                                           (ushort4*)kb, (ushort4*)vb, nullptr);
    gemm_nt<EP_FKR   ><<<gffn, gblk, 0, stream>>>((unsigned short*)kb, wb + 4194304, rb, ab, nullptr, 1024, 0);
    gemm_nt<EP_MULADD><<<g1,   gblk, 0, stream>>>(ab, wb + 9437184, h, nullptr, rb, 4096, 1024);
  }

  ln_kernel<<<NTOK, blk, 0, stream>>>(h, nullptr, nullptr, postw, postb, (float*)d_out);
}